// Round 3
// baseline (380.853 us; speedup 1.0000x reference)
//
#include <hip/hip_runtime.h>
#include <hip/hip_bf16.h>

typedef short short8 __attribute__((ext_vector_type(8)));
typedef float float4v __attribute__((ext_vector_type(4)));

#define HEADS 16
#define HDIM 64
#define TOKDIM 1024
#define SEQ 2048
#define BATCH 2
#define BH (BATCH*HEADS)
#define MROWS (BATCH*SEQ)

__device__ __forceinline__ short f2b(float f) {
    __hip_bfloat16 h = __float2bfloat16(f);
    return *reinterpret_cast<short*>(&h);
}
__device__ __forceinline__ float b2f(short s) {
    __hip_bfloat16 h;
    *reinterpret_cast<short*>(&h) = s;
    return __bfloat162float(h);
}

// load 8 consecutive fp32, round to bf16, pack to short8
__device__ __forceinline__ short8 load8_f32_bf16(const float* __restrict__ p) {
    float4v a = *(const float4v*)p;
    float4v b = *(const float4v*)(p + 4);
    short8 r;
    r[0]=f2b(a[0]); r[1]=f2b(a[1]); r[2]=f2b(a[2]); r[3]=f2b(a[3]);
    r[4]=f2b(b[0]); r[5]=f2b(b[1]); r[6]=f2b(b[2]); r[7]=f2b(b[3]);
    return r;
}

#define BM 128
#define BN 128
#define BK 32
#define LDT 40

// ---------------------------------------------------------------------------
// QKV GEMM: qkv[m][n] = sum_k x[m][k] * wqkv[n][k], fp32 inputs -> bf16 MFMA,
// scatter epilogue into per-head Q/K/V [BH][SEQ][HDIM] bf16 tensors.
// ---------------------------------------------------------------------------
__global__ __launch_bounds__(256)
void gemm_qkv(const float* __restrict__ A, const float* __restrict__ W,
              short* __restrict__ Qo, short* __restrict__ Ko, short* __restrict__ Vo)
{
    __shared__ __align__(16) short As[BM*LDT];
    __shared__ __align__(16) short Bs[BN*LDT];
    const int tid  = threadIdx.x;
    const int lane = tid & 63;
    const int wave = tid >> 6;
    const int wm = wave >> 1, wn = wave & 1;
    const int m0 = blockIdx.x * BM;
    const int n0 = blockIdx.y * BN;
    const int col16 = lane & 15, quad = lane >> 4;
    const int Kdim = TOKDIM;

    float4v acc[4][4];
    #pragma unroll
    for (int i=0;i<4;i++)
        #pragma unroll
        for (int j=0;j<4;j++) acc[i][j] = (float4v){0.f,0.f,0.f,0.f};

    for (int k0 = 0; k0 < Kdim; k0 += BK) {
        __syncthreads();
        #pragma unroll
        for (int s = 0; s < 2; ++s) {
            int blk = tid + s*256;
            int r  = blk >> 2;
            int kb = blk & 3;
            *(short8*)&As[r*LDT + kb*8] = load8_f32_bf16(&A[(size_t)(m0 + r)*Kdim + k0 + kb*8]);
            *(short8*)&Bs[r*LDT + kb*8] = load8_f32_bf16(&W[(size_t)(n0 + r)*Kdim + k0 + kb*8]);
        }
        __syncthreads();
        short8 af[4], bfr[4];
        #pragma unroll
        for (int i=0;i<4;i++) af[i]  = *(const short8*)&As[(wm*64 + i*16 + col16)*LDT + quad*8];
        #pragma unroll
        for (int j=0;j<4;j++) bfr[j] = *(const short8*)&Bs[(wn*64 + j*16 + col16)*LDT + quad*8];
        #pragma unroll
        for (int i=0;i<4;i++)
            #pragma unroll
            for (int j=0;j<4;j++)
                acc[i][j] = __builtin_amdgcn_mfma_f32_16x16x32_bf16(af[i], bfr[j], acc[i][j], 0,0,0);
    }

    #pragma unroll
    for (int i=0;i<4;i++)
        #pragma unroll
        for (int j=0;j<4;j++) {
            const int n = n0 + wn*64 + j*16 + col16;
            const int part = n >> 10;         // 0=Q 1=K 2=V
            const int h = (n & 1023) >> 6;
            const int d = n & 63;
            short* dst = (part == 0) ? Qo : (part == 1) ? Ko : Vo;
            #pragma unroll
            for (int r=0;r<4;r++) {
                const int m = m0 + wm*64 + i*16 + quad*4 + r;
                const int b = m >> 11;
                const int t = m & 2047;
                dst[((size_t)(b*HEADS + h)*SEQ + t)*HDIM + d] = f2b(acc[i][j][r]);
            }
        }
}

// ---------------------------------------------------------------------------
// Out GEMM: out[m][n] = sum_k AO[m][k](bf16) * wout[n][k](fp32->bf16) + bias
// Output written as fp32 (reference output dtype).
// ---------------------------------------------------------------------------
__global__ __launch_bounds__(256)
void gemm_out(const short* __restrict__ A, const float* __restrict__ W,
              const float* __restrict__ bias, float* __restrict__ C)
{
    __shared__ __align__(16) short As[BM*LDT];
    __shared__ __align__(16) short Bs[BN*LDT];
    const int tid  = threadIdx.x;
    const int lane = tid & 63;
    const int wave = tid >> 6;
    const int wm = wave >> 1, wn = wave & 1;
    const int m0 = blockIdx.x * BM;
    const int n0 = blockIdx.y * BN;
    const int col16 = lane & 15, quad = lane >> 4;
    const int Kdim = TOKDIM, Ncols = TOKDIM;

    float4v acc[4][4];
    #pragma unroll
    for (int i=0;i<4;i++)
        #pragma unroll
        for (int j=0;j<4;j++) acc[i][j] = (float4v){0.f,0.f,0.f,0.f};

    for (int k0 = 0; k0 < Kdim; k0 += BK) {
        __syncthreads();
        #pragma unroll
        for (int s = 0; s < 2; ++s) {
            int blk = tid + s*256;
            int r  = blk >> 2;
            int kb = blk & 3;
            *(short8*)&As[r*LDT + kb*8] = *(const short8*)&A[(size_t)(m0 + r)*Kdim + k0 + kb*8];
            *(short8*)&Bs[r*LDT + kb*8] = load8_f32_bf16(&W[(size_t)(n0 + r)*Kdim + k0 + kb*8]);
        }
        __syncthreads();
        short8 af[4], bfr[4];
        #pragma unroll
        for (int i=0;i<4;i++) af[i]  = *(const short8*)&As[(wm*64 + i*16 + col16)*LDT + quad*8];
        #pragma unroll
        for (int j=0;j<4;j++) bfr[j] = *(const short8*)&Bs[(wn*64 + j*16 + col16)*LDT + quad*8];
        #pragma unroll
        for (int i=0;i<4;i++)
            #pragma unroll
            for (int j=0;j<4;j++)
                acc[i][j] = __builtin_amdgcn_mfma_f32_16x16x32_bf16(af[i], bfr[j], acc[i][j], 0,0,0);
    }

    #pragma unroll
    for (int i=0;i<4;i++)
        #pragma unroll
        for (int j=0;j<4;j++) {
            const int n = n0 + wn*64 + j*16 + col16;
            #pragma unroll
            for (int r=0;r<4;r++) {
                const int m = m0 + wm*64 + i*16 + quad*4 + r;
                C[(size_t)m*Ncols + n] = acc[i][j][r] + bias[n];
            }
        }
}

// ---------------------------------------------------------------------------
// V [BH][SEQ][HDIM] bf16 -> Vt [BH][HDIM][SEQ] bf16, 64x64 tiles via LDS
// ---------------------------------------------------------------------------
__global__ __launch_bounds__(256)
void transpose_v(const short* __restrict__ V, short* __restrict__ Vt)
{
    __shared__ short T[64*65];
    const int bh = blockIdx.y;
    const int t0 = blockIdx.x * 64;
    const short* Vb  = V  + (size_t)bh*SEQ*HDIM;
    short*       Vtb = Vt + (size_t)bh*HDIM*SEQ;
    const int tid = threadIdx.x;

    #pragma unroll
    for (int s=0; s<2; ++s) {
        int v = tid + s*256;
        int row = v >> 3, db = v & 7;
        short8 raw = *(const short8*)&Vb[(size_t)(t0+row)*HDIM + db*8];
        #pragma unroll
        for (int j=0;j<8;++j) T[row*65 + db*8 + j] = raw[j];
    }
    __syncthreads();
    #pragma unroll
    for (int s=0; s<2; ++s) {
        int v = tid + s*256;
        int d = v >> 3, tb = v & 7;
        short8 outv;
        #pragma unroll
        for (int j=0;j<8;++j) outv[j] = T[(tb*8+j)*65 + d];
        *(short8*)&Vtb[(size_t)d*SEQ + t0 + tb*8] = outv;
    }
}

// ---------------------------------------------------------------------------
// Flash attention: one block per (bh, 64 q-rows); wave w owns 16 q-rows.
// S = (Q*0.125) @ K^T via MFMA; online softmax; P C-layout -> A-layout via
// per-wave LDS round trip; O += P @ V with Vt B-frags. AO bf16 [4096][1024].
// ---------------------------------------------------------------------------
__global__ __launch_bounds__(256)
void attn_kernel(const short* __restrict__ Q, const short* __restrict__ K,
                 const short* __restrict__ Vt, short* __restrict__ AO)
{
    __shared__ __align__(16) short Plds[4*16*40];
    const int lane = threadIdx.x & 63;
    const int wave = threadIdx.x >> 6;
    const int col16 = lane & 15, quad = lane >> 4;
    const int bh = blockIdx.y;
    const int q0 = blockIdx.x*64 + wave*16;

    const short* Qb = Q  + (size_t)bh*SEQ*HDIM;
    const short* Kb = K  + (size_t)bh*SEQ*HDIM;
    const short* Vb = Vt + (size_t)bh*HDIM*SEQ;

    short8 qf[2];
    #pragma unroll
    for (int kk=0; kk<2; ++kk) {
        short8 raw = *(const short8*)&Qb[(size_t)(q0+col16)*HDIM + kk*32 + quad*8];
        #pragma unroll
        for (int j=0;j<8;++j) raw[j] = f2b(b2f(raw[j]) * 0.125f);
        qf[kk] = raw;
    }

    float4v o[4];
    #pragma unroll
    for (int dt=0;dt<4;dt++) o[dt] = (float4v){0.f,0.f,0.f,0.f};
    float mrun[4] = {-1e30f,-1e30f,-1e30f,-1e30f};
    float lrun[4] = {0.f,0.f,0.f,0.f};

    short* P = &Plds[wave*16*40];

    for (int s0 = 0; s0 < SEQ; s0 += 32) {
        float4v sc[2];
        #pragma unroll
        for (int nt=0; nt<2; ++nt) {
            short8 k0f = *(const short8*)&Kb[(size_t)(s0+nt*16+col16)*HDIM + quad*8];
            short8 k1f = *(const short8*)&Kb[(size_t)(s0+nt*16+col16)*HDIM + 32 + quad*8];
            float4v z = (float4v){0.f,0.f,0.f,0.f};
            z = __builtin_amdgcn_mfma_f32_16x16x32_bf16(qf[0], k0f, z, 0,0,0);
            z = __builtin_amdgcn_mfma_f32_16x16x32_bf16(qf[1], k1f, z, 0,0,0);
            sc[nt] = z;
        }
        float alpha[4];
        #pragma unroll
        for (int r=0;r<4;++r) {
            float mx = fmaxf(sc[0][r], sc[1][r]);
            #pragma unroll
            for (int off=8; off>=1; off>>=1) mx = fmaxf(mx, __shfl_xor(mx, off));
            float mnew = fmaxf(mrun[r], mx);
            alpha[r] = __expf(mrun[r] - mnew);
            float p0 = __expf(sc[0][r] - mnew);
            float p1 = __expf(sc[1][r] - mnew);
            sc[0][r] = p0; sc[1][r] = p1;
            float rs = p0 + p1;
            #pragma unroll
            for (int off=8; off>=1; off>>=1) rs += __shfl_xor(rs, off);
            lrun[r] = lrun[r]*alpha[r] + rs;
            mrun[r] = mnew;
        }
        #pragma unroll
        for (int dt=0;dt<4;dt++)
            #pragma unroll
            for (int r=0;r<4;++r) o[dt][r] *= alpha[r];

        #pragma unroll
        for (int nt=0;nt<2;++nt)
            #pragma unroll
            for (int r=0;r<4;++r)
                P[(quad*4+r)*40 + nt*16 + col16] = f2b(sc[nt][r]);
        __syncthreads();
        short8 pf = *(const short8*)&P[col16*40 + quad*8];
        __syncthreads();

        #pragma unroll
        for (int dt=0;dt<4;++dt) {
            short8 vf = *(const short8*)&Vb[(size_t)(dt*16+col16)*SEQ + s0 + quad*8];
            o[dt] = __builtin_amdgcn_mfma_f32_16x16x32_bf16(pf, vf, o[dt], 0,0,0);
        }
    }

    const int b = bh >> 4, h = bh & 15;
    #pragma unroll
    for (int dt=0;dt<4;++dt)
        #pragma unroll
        for (int r=0;r<4;++r) {
            const int t = q0 + quad*4 + r;
            const size_t idx = ((size_t)(b*SEQ + t))*TOKDIM + h*HDIM + dt*16 + col16;
            AO[idx] = f2b(o[dt][r] / lrun[r]);
        }
}

// ---------------------------------------------------------------------------
extern "C" void kernel_launch(void* const* d_in, const int* in_sizes, int n_in,
                              void* d_out, int out_size, void* d_ws, size_t ws_size,
                              hipStream_t stream)
{
    const float* x    = (const float*)d_in[0];   // [2,2048,1024] fp32
    const float* wqkv = (const float*)d_in[1];   // [3072,1024]   fp32
    const float* wout = (const float*)d_in[2];   // [1024,1024]   fp32
    const float* bout = (const float*)d_in[3];   // [1024]        fp32
    float* out = (float*)d_out;                  // [2,2048,1024] fp32

    char* ws = (char*)d_ws;
    const size_t SZ = (size_t)BH*SEQ*HDIM*sizeof(short);  // 8 MiB per tensor
    short* Qt = (short*)(ws);
    short* Kt = (short*)(ws + SZ);
    short* V  = (short*)(ws + 2*SZ);
    short* Vt = (short*)(ws + 3*SZ);
    short* AO = (short*)(ws + 2*SZ);  // aliases V: V dead after transpose_v

    gemm_qkv<<<dim3(MROWS/BM, (3*TOKDIM)/BN), 256, 0, stream>>>(x, wqkv, Qt, Kt, V);
    transpose_v<<<dim3(SEQ/64, BH), 256, 0, stream>>>(V, Vt);
    attn_kernel<<<dim3(SEQ/64, BH), 256, 0, stream>>>(Qt, Kt, Vt, AO);
    gemm_out<<<dim3(MROWS/BM, TOKDIM/BN), 256, 0, stream>>>(AO, wout, bout, out);
}